// Round 12
// baseline (214.109 us; speedup 1.0000x reference)
//
#include <hip/hip_runtime.h>
#include <hip/hip_bf16.h>
#include <hip/hip_cooperative_groups.h>
#include <stdint.h>

namespace cg = cooperative_groups;

typedef __attribute__((ext_vector_type(4))) float f32x4;
typedef __attribute__((ext_vector_type(8))) short bf16x8;
typedef __attribute__((ext_vector_type(4))) short bf16x4;
typedef __attribute__((ext_vector_type(4))) unsigned int u32x4;

__device__ __forceinline__ unsigned short f2bf_rne(float f) {
  union { float f; unsigned int u; } v; v.f = f;
  unsigned int r = v.u + 0x7FFFu + ((v.u >> 16) & 1u);
  return (unsigned short)(r >> 16);
}
__device__ __forceinline__ float bf2f(unsigned short s) {
  union { float f; unsigned int u; } v; v.u = ((unsigned int)s) << 16;
  return v.f;
}

// ---------------------------------------------------------------------------
// K1: per-batch Gram partials via split bf16 (H H^T + H L^T + L H^T).
// 8 n-chunks of 512 (halved partial traffic: 20.5 MB each way). grid
// (8 chunks, 16 b, 2 row-halves) x 512 thr. Upper-triangle tiles only.
// ---------------------------------------------------------------------------
__global__ __launch_bounds__(512, 4) void k_gram(const float* __restrict__ x,
                                                 float* __restrict__ Gpart) {
  __shared__ __align__(16) unsigned char lds[2][32768];
  const int b = blockIdx.y;
  const int n0 = blockIdx.x << 9;
  const int half = blockIdx.z;
  const int t = threadIdx.x;
  const int lane = t & 63;
  const int w = t >> 6;                    // 0..7
  const int ti = (half << 1) + (w >> 2);   // output tile row 0..3
  const int tj = w & 3;                    // output tile col 0..3
  const int wm = ti << 6;
  const int wn = tj << 6;
  const int row_ld = t >> 1;               // c row this thread stages
  const int nh = t & 1;                    // 16-float half of the 32-n sub
  const int lrow = lane & 15;
  const int lkg = lane >> 4;

  f32x4 acc[4][4];
#pragma unroll
  for (int i = 0; i < 4; i++)
#pragma unroll
    for (int j = 0; j < 4; j++) acc[i][j] = (f32x4){0.f, 0.f, 0.f, 0.f};

  const float* gx = x + (((size_t)(b * 256 + row_ld)) << 12) + n0 + (nh << 4);

  for (int sub = 0; sub < 16; sub++) {
    unsigned char* buf = lds[sub & 1];
    f32x4 v0 = *(const f32x4*)(gx + (sub << 5));
    f32x4 v1 = *(const f32x4*)(gx + (sub << 5) + 4);
    f32x4 v2 = *(const f32x4*)(gx + (sub << 5) + 8);
    f32x4 v3 = *(const f32x4*)(gx + (sub << 5) + 12);
    float vv[16] = {v0[0], v0[1], v0[2], v0[3], v1[0], v1[1], v1[2], v1[3],
                    v2[0], v2[1], v2[2], v2[3], v3[0], v3[1], v3[2], v3[3]};
    unsigned short hi[16], lo[16];
#pragma unroll
    for (int j = 0; j < 16; j++) {
      hi[j] = f2bf_rne(vv[j]);
      lo[j] = f2bf_rne(vv[j] - bf2f(hi[j]));
    }
    u32x4 hw0 = {(unsigned)hi[0] | ((unsigned)hi[1] << 16),
                 (unsigned)hi[2] | ((unsigned)hi[3] << 16),
                 (unsigned)hi[4] | ((unsigned)hi[5] << 16),
                 (unsigned)hi[6] | ((unsigned)hi[7] << 16)};
    u32x4 hw1 = {(unsigned)hi[8] | ((unsigned)hi[9] << 16),
                 (unsigned)hi[10] | ((unsigned)hi[11] << 16),
                 (unsigned)hi[12] | ((unsigned)hi[13] << 16),
                 (unsigned)hi[14] | ((unsigned)hi[15] << 16)};
    u32x4 lw0 = {(unsigned)lo[0] | ((unsigned)lo[1] << 16),
                 (unsigned)lo[2] | ((unsigned)lo[3] << 16),
                 (unsigned)lo[4] | ((unsigned)lo[5] << 16),
                 (unsigned)lo[6] | ((unsigned)lo[7] << 16)};
    u32x4 lw1 = {(unsigned)lo[8] | ((unsigned)lo[9] << 16),
                 (unsigned)lo[10] | ((unsigned)lo[11] << 16),
                 (unsigned)lo[12] | ((unsigned)lo[13] << 16),
                 (unsigned)lo[14] | ((unsigned)lo[15] << 16)};
    const int swz = (row_ld & 7) << 4;
    unsigned char* rbase = buf + row_ld * 128;
    *(u32x4*)(rbase + (((nh << 5)) ^ swz)) = hw0;            // H region
    *(u32x4*)(rbase + (((nh << 5) + 16) ^ swz)) = hw1;
    *(u32x4*)(rbase + ((64 + (nh << 5)) ^ swz)) = lw0;       // L region
    *(u32x4*)(rbase + ((64 + (nh << 5) + 16) ^ swz)) = lw1;
    __syncthreads();  // dbuf: one barrier/sub

    bf16x8 bh[4], bl[4];
#pragma unroll
    for (int nf = 0; nf < 4; nf++) {
      int col = wn + (nf << 4) + lrow;
      int cs = (col & 7) << 4;
      bh[nf] = *(const bf16x8*)(buf + col * 128 + (((lkg << 4)) ^ cs));
      bl[nf] = *(const bf16x8*)(buf + col * 128 + ((64 + (lkg << 4)) ^ cs));
    }
#pragma unroll
    for (int mf = 0; mf < 4; mf++) {
      int row = wm + (mf << 4) + lrow;
      int rs = (row & 7) << 4;
      bf16x8 ah = *(const bf16x8*)(buf + row * 128 + (((lkg << 4)) ^ rs));
      bf16x8 al = *(const bf16x8*)(buf + row * 128 + ((64 + (lkg << 4)) ^ rs));
#pragma unroll
      for (int nf = 0; nf < 4; nf++) {
        acc[mf][nf] = __builtin_amdgcn_mfma_f32_16x16x32_bf16(ah, bh[nf], acc[mf][nf], 0, 0, 0);
        acc[mf][nf] = __builtin_amdgcn_mfma_f32_16x16x32_bf16(ah, bl[nf], acc[mf][nf], 0, 0, 0);
        acc[mf][nf] = __builtin_amdgcn_mfma_f32_16x16x32_bf16(al, bh[nf], acc[mf][nf], 0, 0, 0);
      }
    }
  }

  if (tj >= ti) {  // upper-triangle tiles only (G symmetric)
    float* Gp = Gpart + (((size_t)(blockIdx.x * 16 + b)) << 16);
#pragma unroll
    for (int mf = 0; mf < 4; mf++)
#pragma unroll
      for (int nf = 0; nf < 4; nf++) {
        int col = wn + (nf << 4) + lrow;
#pragma unroll
        for (int r = 0; r < 4; r++) {
          int row = wm + (mf << 4) + (lkg << 2) + r;
          Gp[row * 256 + col] = acc[mf][nf][r];
        }
      }
  }
}

// ---------------------------------------------------------------------------
// K2 (cooperative, fused reduce+scores): Phase A — blocks 0..159 = (b, upper
// tile i<=j): sum the 8 chunk-partials, write G tile + transposed mirror.
// __threadfence + grid sync (device-scope visibility across XCD L2s).
// Phase B — block = (h, b, dg): T = Wq·G (wave-uniform scalar Wq loads),
// LDS reduce, scores+softmax -> attn, Wout rows. grid 256 x 512.
// ---------------------------------------------------------------------------
__global__ __launch_bounds__(512) void k_redscores(const float* __restrict__ wq,
                                                   const float* __restrict__ wk,
                                                   const float* __restrict__ wv,
                                                   const float* __restrict__ Gpart,
                                                   float* __restrict__ G,
                                                   float* __restrict__ attn,
                                                   unsigned short* __restrict__ Wout) {
  __shared__ float part[8][16][256];  // 128 KB; phase A aliases a corner as tl
  const int bx = blockIdx.x;
  const int t = threadIdx.x, lane = t & 63;

  // ---- Phase A: reduce Gpart -> G (160 active blocks) ----
  if (bx < 160) {
    const int b = bx / 10;
    const int tp = bx % 10;
    const int TI[10] = {0, 0, 0, 0, 1, 1, 1, 2, 2, 3};
    const int TJ[10] = {0, 1, 2, 3, 1, 2, 3, 2, 3, 3};
    const int i = TI[tp], j = TJ[tp];
    float (*tl)[68] = (float(*)[68]) & part[0][0][0];  // 64x68 f32 = 17 KB
#pragma unroll
    for (int u = 0; u < 2; u++) {
      int o = t * 2 + u;               // 1024 quads: 64 rows x 16 quad-cols
      int r = o >> 4, cq = o & 15;
      const float* src = Gpart + ((size_t)b << 16) + (size_t)(i * 64 + r) * 256 + j * 64 + (cq << 2);
      f32x4 s = *(const f32x4*)src;
#pragma unroll
      for (int ch = 1; ch < 8; ch++)
        s += *(const f32x4*)(src + (((size_t)ch) << 20));
      *(f32x4*)(G + ((size_t)b << 16) + (size_t)(i * 64 + r) * 256 + j * 64 + (cq << 2)) = s;
      if (i != j) *(f32x4*)&tl[r][cq << 2] = s;
    }
    if (i != j) {
      __syncthreads();
#pragma unroll
      for (int u = 0; u < 2; u++) {
        int o = t * 2 + u;             // 1024: 64 mirror-rows x 16 quad-groups
        int c = o >> 4, g = o & 15;
        f32x4 m;
#pragma unroll
        for (int q = 0; q < 4; q++) m[q] = tl[(g << 2) + q][c];
        *(f32x4*)(G + ((size_t)b << 16) + (size_t)(j * 64 + c) * 256 + i * 64 + (g << 2)) = m;
      }
    }
  }
  __threadfence();
  cg::this_grid().sync();

  // ---- Phase B: scores (verbatim k_scores; h,b,dg decoded from bx) ----
  const int h = bx & 7, b = (bx >> 3) & 15, dg = bx >> 7;
  const int wu = __builtin_amdgcn_readfirstlane(t >> 6);

  const float* wqrow = wq + (size_t)(h * 32 + dg * 16) * 256 + wu * 32;  // uniform
  f32x4 tp[16];
#pragma unroll
  for (int d = 0; d < 16; d++) tp[d] = (f32x4){0.f, 0.f, 0.f, 0.f};

  const float* Gb = G + ((size_t)b << 16) + (size_t)(wu * 32) * 256 + (lane << 2);
  for (int s = 0; s < 32; s++) {
    f32x4 g = *(const f32x4*)(Gb + s * 256);
#pragma unroll
    for (int d = 0; d < 16; d++)
      tp[d] += g * wqrow[d * 256 + s];  // uniform index -> s_load (SMEM pipe)
  }
#pragma unroll
  for (int d = 0; d < 16; d++)
    *(f32x4*)&part[wu][d][lane << 2] = tp[d];
  __syncthreads();

#pragma unroll
  for (int u = 0; u < 2; u++) {
    int o = t * 2 + u;  // [0,1024) = 16 d x 64 quads
    int d = o >> 6, q = (o & 63) << 2;
    f32x4 s = *(f32x4*)&part[0][d][q];
#pragma unroll
    for (int w2 = 1; w2 < 8; w2++) s += *(f32x4*)&part[w2][d][q];
    *(f32x4*)&part[0][d][q] = s;
  }
  __syncthreads();
  const float* Tb = &part[0][0][0];

  const int dls = t >> 5, es = t & 31;
  f32x4 sa = {0.f, 0.f, 0.f, 0.f};
  const float* Tr = Tb + dls * 256;
  const float* wkr = wk + (size_t)(h * 32 + es) * 256;
  for (int c4 = 0; c4 < 64; c4++)
    sa += *(const f32x4*)(Tr + (c4 << 2)) * *(const f32x4*)(wkr + (c4 << 2));
  float s = (sa[0] + sa[1] + sa[2] + sa[3]) * 0.35355339059327379f;

  float m = s;
#pragma unroll
  for (int off = 1; off < 32; off <<= 1) m = fmaxf(m, __shfl_xor(m, off));
  float p = expf(s - m);
  float su = p;
#pragma unroll
  for (int off = 1; off < 32; off <<= 1) su += __shfl_xor(su, off);
  float a = p / su;
  attn[(((b * 8 + h) * 32) + dg * 16 + dls) * 32 + es] = a;

  f32x4 o0 = {0.f, 0.f, 0.f, 0.f}, o1 = {0.f, 0.f, 0.f, 0.f};
  const float* wvh = wv + (size_t)(h * 32) * 256 + (lane << 2);
#pragma unroll
  for (int e = 0; e < 32; e++) {
    float a0 = __shfl(a, e);
    float a1 = __shfl(a, 32 + e);
    f32x4 vv = *(const f32x4*)(wvh + e * 256);
    o0 += vv * a0;
    o1 += vv * a1;
  }
  const int d0 = dg * 16 + 2 * wu;
  const int co0 = d0 * 8 + h, co1 = (d0 + 1) * 8 + h;
  o0 += *(const f32x4*)(wv + (size_t)co0 * 256 + (lane << 2));
  o1 += *(const f32x4*)(wv + (size_t)co1 * 256 + (lane << 2));
  bf16x4 p0, p1;
#pragma unroll
  for (int j = 0; j < 4; j++) {
    p0[j] = (short)f2bf_rne(o0[j]);
    p1[j] = (short)f2bf_rne(o1[j]);
  }
  *(bf16x4*)(Wout + ((size_t)(b * 256 + co0) << 8) + (lane << 2)) = p0;
  *(bf16x4*)(Wout + ((size_t)(b * 256 + co1) << 8) + (lane << 2)) = p1;
}

// ---------------------------------------------------------------------------
// K3: out[b] = W_out_b (bf16) x bf16(x[b]), fp32 out. x read fp32 (L3-hot),
// converted in-kernel; double-buffered Bt (1 barrier/kt); tr_b16 B-frag path.
// grid (32 n-chunks, 16 b) x 512 thr.
// ---------------------------------------------------------------------------
__global__ __launch_bounds__(512) void k_out(const float* __restrict__ x,
                                             const unsigned short* __restrict__ Wout,
                                             float* __restrict__ out) {
  __shared__ __align__(16) unsigned short Bt[2][4096];  // 2 x (32c x 128n)
  const int b = blockIdx.y;
  const int nb = blockIdx.x << 7;
  const int t = threadIdx.x;
  const int lane = t & 63;
  const int w = t >> 6;
  const int wm = (w >> 1) << 6;
  const int wn = (w & 1) << 6;
  const int lrow = lane & 15;
  const int lkg = lane >> 4;

  f32x4 acc[4][4];
#pragma unroll
  for (int i = 0; i < 4; i++)
#pragma unroll
    for (int j = 0; j < 4; j++) acc[i][j] = (f32x4){0.f, 0.f, 0.f, 0.f};

  // staging lane map (m173 pattern): linear LDS dest <- permuted global src
  const int pos = lane >> 3;
  const int cblk = 2 * (pos & 3) + (pos >> 2);  // even cblks first, then odd
  const int ctil = cblk * 4 + ((lane & 7) >> 1);
  const int noff = (lane & 1) << 3;
  const float* gxb = x + (((size_t)b) << 20) + (size_t)ctil * 4096 + nb + (w << 4) + noff;
  const unsigned int bt0 = (unsigned int)(uintptr_t)(&Bt[0][0]);

  f32x4 xa = *(const f32x4*)(gxb);
  f32x4 xb = *(const f32x4*)(gxb + 4);

  for (int kt = 0; kt < 8; kt++) {
    const int p = kt & 1;
    bf16x8 pk;
#pragma unroll
    for (int j = 0; j < 4; j++) {
      pk[j] = (short)f2bf_rne(xa[j]);
      pk[4 + j] = (short)f2bf_rne(xb[j]);
    }
    *(bf16x8*)(&Bt[p][(w << 9) + (lane << 3)]) = pk;
    __syncthreads();  // single barrier/kt

    if (kt < 7) {  // prefetch next k-tile under MFMA
      const float* nx = gxb + (((size_t)(kt + 1)) << 17);
      xa = *(const f32x4*)(nx);
      xb = *(const f32x4*)(nx + 4);
    }

    bf16x8 afr[4];
    const unsigned short* wrow = Wout + (((size_t)(b * 256)) << 8) + kt * 32 + (lkg << 3);
#pragma unroll
    for (int mf = 0; mf < 4; mf++) {
      int co = wm + (mf << 4) + lrow;
      afr[mf] = *(const bf16x8*)(wrow + ((size_t)co << 8));
    }

    bf16x4 t0[4], t1[4];
#pragma unroll
    for (int nf = 0; nf < 4; nf++) {
      unsigned int base = bt0 + (unsigned int)(p << 13) +
                          (unsigned int)((((wn >> 4) + nf)) << 10) + (lane << 3);
      asm volatile("ds_read_b64_tr_b16 %0, %1" : "=v"(t0[nf]) : "v"(base) : "memory");
      asm volatile("ds_read_b64_tr_b16 %0, %1 offset:512" : "=v"(t1[nf]) : "v"(base) : "memory");
    }
    asm volatile("s_waitcnt lgkmcnt(0)" ::: "memory");
    __builtin_amdgcn_sched_barrier(0);

    bf16x8 bfr[4];
#pragma unroll
    for (int nf = 0; nf < 4; nf++) {
      bfr[nf][0] = t0[nf][0]; bfr[nf][1] = t0[nf][1];
      bfr[nf][2] = t0[nf][2]; bfr[nf][3] = t0[nf][3];
      bfr[nf][4] = t1[nf][0]; bfr[nf][5] = t1[nf][1];
      bfr[nf][6] = t1[nf][2]; bfr[nf][7] = t1[nf][3];
    }
#pragma unroll
    for (int mf = 0; mf < 4; mf++)
#pragma unroll
      for (int nf = 0; nf < 4; nf++)
        acc[mf][nf] = __builtin_amdgcn_mfma_f32_16x16x32_bf16(afr[mf], bfr[nf], acc[mf][nf], 0, 0, 0);
  }

  float* ob = out + (((size_t)b) << 20) + nb;
#pragma unroll
  for (int mf = 0; mf < 4; mf++)
#pragma unroll
    for (int nf = 0; nf < 4; nf++) {
      int col = wn + (nf << 4) + lrow;
#pragma unroll
      for (int r = 0; r < 4; r++) {
        int row = wm + (mf << 4) + (lkg << 2) + r;
        ob[((size_t)row << 12) + col] = acc[mf][nf][r];
      }
    }
}

// ---------------------------------------------------------------------------
extern "C" void kernel_launch(void* const* d_in, const int* in_sizes, int n_in,
                              void* d_out, int out_size, void* d_ws, size_t ws_size,
                              hipStream_t stream) {
  const float* x = (const float*)d_in[0];
  const float* wq = (const float*)d_in[1];
  const float* wk = (const float*)d_in[2];
  const float* wv = (const float*)d_in[3];
  float* out = (float*)d_out;
  float* attn = out + (size_t)16 * 256 * 4096;

  // Gram partials (8 chunks x 16 b x 256 KB = 33.5 MB) live in the
  // dead-until-K3 out region; attn tail is disjoint.
  float* Gpart = out;

  char* ws = (char*)d_ws;
  float* G = (float*)ws;                                     // 4 MB
  unsigned short* Wout = (unsigned short*)(ws + (4 << 20));  // 2 MB

  k_gram<<<dim3(8, 16, 2), dim3(512), 0, stream>>>(x, Gpart);

  void* args[] = {(void*)&wq, (void*)&wk, (void*)&wv, (void*)&Gpart,
                  (void*)&G, (void*)&attn, (void*)&Wout};
  hipLaunchCooperativeKernel((const void*)k_redscores, dim3(256), dim3(512),
                             args, 0, stream);

  k_out<<<dim3(32, 16), dim3(512), 0, stream>>>(x, Wout, out);
}

// Round 13
// 126.482 us; speedup vs baseline: 1.6928x; 1.6928x over previous
//
#include <hip/hip_runtime.h>
#include <hip/hip_bf16.h>
#include <stdint.h>

typedef __attribute__((ext_vector_type(4))) float f32x4;
typedef __attribute__((ext_vector_type(8))) short bf16x8;
typedef __attribute__((ext_vector_type(4))) short bf16x4;
typedef __attribute__((ext_vector_type(4))) unsigned int u32x4;

__device__ __forceinline__ unsigned short f2bf_rne(float f) {
  union { float f; unsigned int u; } v; v.f = f;
  unsigned int r = v.u + 0x7FFFu + ((v.u >> 16) & 1u);
  return (unsigned short)(r >> 16);
}
__device__ __forceinline__ float bf2f(unsigned short s) {
  union { float f; unsigned int u; } v; v.u = ((unsigned int)s) << 16;
  return v.f;
}

// ---------------------------------------------------------------------------
// K1: per-batch Gram partials via split bf16 (H H^T + H L^T + L H^T).
// 8 n-chunks of 512. grid (8 chunks, 16 b, 2 row-halves) x 512 thr.
// Stores ALL 16 tiles (full Gram per chunk) -> downstream needs no mirrors
// and no reduce kernel: k_scores sums the 8 chunks inline.
// ---------------------------------------------------------------------------
__global__ __launch_bounds__(512, 4) void k_gram(const float* __restrict__ x,
                                                 float* __restrict__ Gpart) {
  __shared__ __align__(16) unsigned char lds[2][32768];
  const int b = blockIdx.y;
  const int n0 = blockIdx.x << 9;
  const int half = blockIdx.z;
  const int t = threadIdx.x;
  const int lane = t & 63;
  const int w = t >> 6;                    // 0..7
  const int ti = (half << 1) + (w >> 2);   // output tile row 0..3
  const int tj = w & 3;                    // output tile col 0..3
  const int wm = ti << 6;
  const int wn = tj << 6;
  const int row_ld = t >> 1;               // c row this thread stages
  const int nh = t & 1;                    // 16-float half of the 32-n sub
  const int lrow = lane & 15;
  const int lkg = lane >> 4;

  f32x4 acc[4][4];
#pragma unroll
  for (int i = 0; i < 4; i++)
#pragma unroll
    for (int j = 0; j < 4; j++) acc[i][j] = (f32x4){0.f, 0.f, 0.f, 0.f};

  const float* gx = x + (((size_t)(b * 256 + row_ld)) << 12) + n0 + (nh << 4);

  for (int sub = 0; sub < 16; sub++) {
    unsigned char* buf = lds[sub & 1];
    f32x4 v0 = *(const f32x4*)(gx + (sub << 5));
    f32x4 v1 = *(const f32x4*)(gx + (sub << 5) + 4);
    f32x4 v2 = *(const f32x4*)(gx + (sub << 5) + 8);
    f32x4 v3 = *(const f32x4*)(gx + (sub << 5) + 12);
    float vv[16] = {v0[0], v0[1], v0[2], v0[3], v1[0], v1[1], v1[2], v1[3],
                    v2[0], v2[1], v2[2], v2[3], v3[0], v3[1], v3[2], v3[3]};
    unsigned short hi[16], lo[16];
#pragma unroll
    for (int j = 0; j < 16; j++) {
      hi[j] = f2bf_rne(vv[j]);
      lo[j] = f2bf_rne(vv[j] - bf2f(hi[j]));
    }
    u32x4 hw0 = {(unsigned)hi[0] | ((unsigned)hi[1] << 16),
                 (unsigned)hi[2] | ((unsigned)hi[3] << 16),
                 (unsigned)hi[4] | ((unsigned)hi[5] << 16),
                 (unsigned)hi[6] | ((unsigned)hi[7] << 16)};
    u32x4 hw1 = {(unsigned)hi[8] | ((unsigned)hi[9] << 16),
                 (unsigned)hi[10] | ((unsigned)hi[11] << 16),
                 (unsigned)hi[12] | ((unsigned)hi[13] << 16),
                 (unsigned)hi[14] | ((unsigned)hi[15] << 16)};
    u32x4 lw0 = {(unsigned)lo[0] | ((unsigned)lo[1] << 16),
                 (unsigned)lo[2] | ((unsigned)lo[3] << 16),
                 (unsigned)lo[4] | ((unsigned)lo[5] << 16),
                 (unsigned)lo[6] | ((unsigned)lo[7] << 16)};
    u32x4 lw1 = {(unsigned)lo[8] | ((unsigned)lo[9] << 16),
                 (unsigned)lo[10] | ((unsigned)lo[11] << 16),
                 (unsigned)lo[12] | ((unsigned)lo[13] << 16),
                 (unsigned)lo[14] | ((unsigned)lo[15] << 16)};
    const int swz = (row_ld & 7) << 4;
    unsigned char* rbase = buf + row_ld * 128;
    *(u32x4*)(rbase + (((nh << 5)) ^ swz)) = hw0;            // H region
    *(u32x4*)(rbase + (((nh << 5) + 16) ^ swz)) = hw1;
    *(u32x4*)(rbase + ((64 + (nh << 5)) ^ swz)) = lw0;       // L region
    *(u32x4*)(rbase + ((64 + (nh << 5) + 16) ^ swz)) = lw1;
    __syncthreads();  // dbuf: one barrier/sub

    bf16x8 bh[4], bl[4];
#pragma unroll
    for (int nf = 0; nf < 4; nf++) {
      int col = wn + (nf << 4) + lrow;
      int cs = (col & 7) << 4;
      bh[nf] = *(const bf16x8*)(buf + col * 128 + (((lkg << 4)) ^ cs));
      bl[nf] = *(const bf16x8*)(buf + col * 128 + ((64 + (lkg << 4)) ^ cs));
    }
#pragma unroll
    for (int mf = 0; mf < 4; mf++) {
      int row = wm + (mf << 4) + lrow;
      int rs = (row & 7) << 4;
      bf16x8 ah = *(const bf16x8*)(buf + row * 128 + (((lkg << 4)) ^ rs));
      bf16x8 al = *(const bf16x8*)(buf + row * 128 + ((64 + (lkg << 4)) ^ rs));
#pragma unroll
      for (int nf = 0; nf < 4; nf++) {
        acc[mf][nf] = __builtin_amdgcn_mfma_f32_16x16x32_bf16(ah, bh[nf], acc[mf][nf], 0, 0, 0);
        acc[mf][nf] = __builtin_amdgcn_mfma_f32_16x16x32_bf16(ah, bl[nf], acc[mf][nf], 0, 0, 0);
        acc[mf][nf] = __builtin_amdgcn_mfma_f32_16x16x32_bf16(al, bh[nf], acc[mf][nf], 0, 0, 0);
      }
    }
  }

  float* Gp = Gpart + (((size_t)(blockIdx.x * 16 + b)) << 16);
#pragma unroll
  for (int mf = 0; mf < 4; mf++)
#pragma unroll
    for (int nf = 0; nf < 4; nf++) {
      int col = wn + (nf << 4) + lrow;
#pragma unroll
      for (int r = 0; r < 4; r++) {
        int row = wm + (mf << 4) + (lkg << 2) + r;
        Gp[row * 256 + col] = acc[mf][nf][r];
      }
    }
}

// ---------------------------------------------------------------------------
// K2: T = Wq_rows·G with G summed INLINE from the 8 Gpart chunks (L3-hot;
// ch order 0..7 = bitwise-identical to the old k_reduce). Then scores +
// softmax -> attn; Wout rows via shfl(A) + coalesced Wv rows.
// grid (8 h, 16 b, 2 dg) x 512.
// ---------------------------------------------------------------------------
__global__ __launch_bounds__(512) void k_scores(const float* __restrict__ wq,
                                                const float* __restrict__ wk,
                                                const float* __restrict__ wv,
                                                const float* __restrict__ Gpart,
                                                float* __restrict__ attn,
                                                unsigned short* __restrict__ Wout) {
  __shared__ float part[8][16][256];  // 128 KB; part[0] becomes T after reduce
  const int h = blockIdx.x, b = blockIdx.y, dg = blockIdx.z;
  const int t = threadIdx.x, lane = t & 63;
  const int wu = __builtin_amdgcn_readfirstlane(t >> 6);  // wave id, uniform

  // ---- Phase 1: T[d][cp] = sum_c Wq[h*32+dg*16+d][c] * (sum_ch Gpart) ----
  const float* wqrow = wq + (size_t)(h * 32 + dg * 16) * 256 + wu * 32;  // uniform
  f32x4 tp[16];
#pragma unroll
  for (int d = 0; d < 16; d++) tp[d] = (f32x4){0.f, 0.f, 0.f, 0.f};

  const float* Gb = Gpart + ((size_t)b << 16) + (size_t)(wu * 32) * 256 + (lane << 2);
  for (int s = 0; s < 32; s++) {
    f32x4 g = *(const f32x4*)(Gb + s * 256);
#pragma unroll
    for (int ch = 1; ch < 8; ch++)
      g += *(const f32x4*)(Gb + (((size_t)ch) << 20) + s * 256);
#pragma unroll
    for (int d = 0; d < 16; d++)
      tp[d] += g * wqrow[d * 256 + s];  // uniform index -> s_load (SMEM pipe)
  }
#pragma unroll
  for (int d = 0; d < 16; d++)
    *(f32x4*)&part[wu][d][lane << 2] = tp[d];
  __syncthreads();

  // in-place reduce into part[0]: each thread owns 2 f32x4 output slots
#pragma unroll
  for (int u = 0; u < 2; u++) {
    int o = t * 2 + u;  // [0,1024) = 16 d x 64 quads
    int d = o >> 6, q = (o & 63) << 2;
    f32x4 s = *(f32x4*)&part[0][d][q];
#pragma unroll
    for (int w2 = 1; w2 < 8; w2++) s += *(f32x4*)&part[w2][d][q];
    *(f32x4*)&part[0][d][q] = s;
  }
  __syncthreads();
  const float* Tb = &part[0][0][0];

  // ---- Phase 2: scores + softmax (thread = (dls = t>>5, es = t&31)) ----
  const int dls = t >> 5, es = t & 31;
  f32x4 sa = {0.f, 0.f, 0.f, 0.f};
  const float* Tr = Tb + dls * 256;
  const float* wkr = wk + (size_t)(h * 32 + es) * 256;
  for (int c4 = 0; c4 < 64; c4++)
    sa += *(const f32x4*)(Tr + (c4 << 2)) * *(const f32x4*)(wkr + (c4 << 2));
  float s = (sa[0] + sa[1] + sa[2] + sa[3]) * 0.35355339059327379f;

  float m = s;
#pragma unroll
  for (int off = 1; off < 32; off <<= 1) m = fmaxf(m, __shfl_xor(m, off));
  float p = expf(s - m);
  float su = p;
#pragma unroll
  for (int off = 1; off < 32; off <<= 1) su += __shfl_xor(su, off);
  float a = p / su;
  attn[(((b * 8 + h) * 32) + dg * 16 + dls) * 32 + es] = a;

  // ---- Phase 3: wave wu owns rows {2wu, 2wu+1}; A broadcast via shfl ----
  f32x4 o0 = {0.f, 0.f, 0.f, 0.f}, o1 = {0.f, 0.f, 0.f, 0.f};
  const float* wvh = wv + (size_t)(h * 32) * 256 + (lane << 2);
#pragma unroll
  for (int e = 0; e < 32; e++) {
    float a0 = __shfl(a, e);
    float a1 = __shfl(a, 32 + e);
    f32x4 vv = *(const f32x4*)(wvh + e * 256);
    o0 += vv * a0;
    o1 += vv * a1;
  }
  const int d0 = dg * 16 + 2 * wu;
  const int co0 = d0 * 8 + h, co1 = (d0 + 1) * 8 + h;
  o0 += *(const f32x4*)(wv + (size_t)co0 * 256 + (lane << 2));
  o1 += *(const f32x4*)(wv + (size_t)co1 * 256 + (lane << 2));
  bf16x4 p0, p1;
#pragma unroll
  for (int j = 0; j < 4; j++) {
    p0[j] = (short)f2bf_rne(o0[j]);
    p1[j] = (short)f2bf_rne(o1[j]);
  }
  *(bf16x4*)(Wout + ((size_t)(b * 256 + co0) << 8) + (lane << 2)) = p0;
  *(bf16x4*)(Wout + ((size_t)(b * 256 + co1) << 8) + (lane << 2)) = p1;
}

// ---------------------------------------------------------------------------
// K3: out[b] = W_out_b (bf16) x bf16(x[b]), fp32 out. x read fp32 (L3-hot),
// converted in-kernel; double-buffered Bt (1 barrier/kt); tr_b16 B-frag path.
// grid (32 n-chunks, 16 b) x 512 thr.
// ---------------------------------------------------------------------------
__global__ __launch_bounds__(512) void k_out(const float* __restrict__ x,
                                             const unsigned short* __restrict__ Wout,
                                             float* __restrict__ out) {
  __shared__ __align__(16) unsigned short Bt[2][4096];  // 2 x (32c x 128n)
  const int b = blockIdx.y;
  const int nb = blockIdx.x << 7;
  const int t = threadIdx.x;
  const int lane = t & 63;
  const int w = t >> 6;
  const int wm = (w >> 1) << 6;
  const int wn = (w & 1) << 6;
  const int lrow = lane & 15;
  const int lkg = lane >> 4;

  f32x4 acc[4][4];
#pragma unroll
  for (int i = 0; i < 4; i++)
#pragma unroll
    for (int j = 0; j < 4; j++) acc[i][j] = (f32x4){0.f, 0.f, 0.f, 0.f};

  // staging lane map (m173 pattern): linear LDS dest <- permuted global src
  const int pos = lane >> 3;
  const int cblk = 2 * (pos & 3) + (pos >> 2);  // even cblks first, then odd
  const int ctil = cblk * 4 + ((lane & 7) >> 1);
  const int noff = (lane & 1) << 3;
  const float* gxb = x + (((size_t)b) << 20) + (size_t)ctil * 4096 + nb + (w << 4) + noff;
  const unsigned int bt0 = (unsigned int)(uintptr_t)(&Bt[0][0]);

  f32x4 xa = *(const f32x4*)(gxb);
  f32x4 xb = *(const f32x4*)(gxb + 4);

  for (int kt = 0; kt < 8; kt++) {
    const int p = kt & 1;
    bf16x8 pk;
#pragma unroll
    for (int j = 0; j < 4; j++) {
      pk[j] = (short)f2bf_rne(xa[j]);
      pk[4 + j] = (short)f2bf_rne(xb[j]);
    }
    *(bf16x8*)(&Bt[p][(w << 9) + (lane << 3)]) = pk;
    __syncthreads();  // single barrier/kt

    if (kt < 7) {  // prefetch next k-tile under MFMA
      const float* nx = gxb + (((size_t)(kt + 1)) << 17);
      xa = *(const f32x4*)(nx);
      xb = *(const f32x4*)(nx + 4);
    }

    bf16x8 afr[4];
    const unsigned short* wrow = Wout + (((size_t)(b * 256)) << 8) + kt * 32 + (lkg << 3);
#pragma unroll
    for (int mf = 0; mf < 4; mf++) {
      int co = wm + (mf << 4) + lrow;
      afr[mf] = *(const bf16x8*)(wrow + ((size_t)co << 8));
    }

    bf16x4 t0[4], t1[4];
#pragma unroll
    for (int nf = 0; nf < 4; nf++) {
      unsigned int base = bt0 + (unsigned int)(p << 13) +
                          (unsigned int)((((wn >> 4) + nf)) << 10) + (lane << 3);
      asm volatile("ds_read_b64_tr_b16 %0, %1" : "=v"(t0[nf]) : "v"(base) : "memory");
      asm volatile("ds_read_b64_tr_b16 %0, %1 offset:512" : "=v"(t1[nf]) : "v"(base) : "memory");
    }
    asm volatile("s_waitcnt lgkmcnt(0)" ::: "memory");
    __builtin_amdgcn_sched_barrier(0);

    bf16x8 bfr[4];
#pragma unroll
    for (int nf = 0; nf < 4; nf++) {
      bfr[nf][0] = t0[nf][0]; bfr[nf][1] = t0[nf][1];
      bfr[nf][2] = t0[nf][2]; bfr[nf][3] = t0[nf][3];
      bfr[nf][4] = t1[nf][0]; bfr[nf][5] = t1[nf][1];
      bfr[nf][6] = t1[nf][2]; bfr[nf][7] = t1[nf][3];
    }
#pragma unroll
    for (int mf = 0; mf < 4; mf++)
#pragma unroll
      for (int nf = 0; nf < 4; nf++)
        acc[mf][nf] = __builtin_amdgcn_mfma_f32_16x16x32_bf16(afr[mf], bfr[nf], acc[mf][nf], 0, 0, 0);
  }

  float* ob = out + (((size_t)b) << 20) + nb;
#pragma unroll
  for (int mf = 0; mf < 4; mf++)
#pragma unroll
    for (int nf = 0; nf < 4; nf++) {
      int col = wn + (nf << 4) + lrow;
#pragma unroll
      for (int r = 0; r < 4; r++) {
        int row = wm + (mf << 4) + (lkg << 2) + r;
        ob[((size_t)row << 12) + col] = acc[mf][nf][r];
      }
    }
}

// ---------------------------------------------------------------------------
extern "C" void kernel_launch(void* const* d_in, const int* in_sizes, int n_in,
                              void* d_out, int out_size, void* d_ws, size_t ws_size,
                              hipStream_t stream) {
  const float* x = (const float*)d_in[0];
  const float* wq = (const float*)d_in[1];
  const float* wk = (const float*)d_in[2];
  const float* wv = (const float*)d_in[3];
  float* out = (float*)d_out;
  float* attn = out + (size_t)16 * 256 * 4096;

  // Gpart: 8 chunks x 16 b x 256 KB = 33.5 MB, lives in the dead-until-K3
  // out region (attn tail is disjoint); consumed by k_scores before k_out.
  float* Gpart = out;

  char* ws = (char*)d_ws;
  unsigned short* Wout = (unsigned short*)ws;  // 2 MB

  k_gram<<<dim3(8, 16, 2), dim3(512), 0, stream>>>(x, Gpart);
  k_scores<<<dim3(8, 16, 2), dim3(512), 0, stream>>>(wq, wk, wv, Gpart, attn, Wout);
  k_out<<<dim3(32, 16), dim3(512), 0, stream>>>(x, Wout, out);
}

// Round 14
// 101.922 us; speedup vs baseline: 2.1007x; 1.2410x over previous
//
#include <hip/hip_runtime.h>
#include <hip/hip_bf16.h>
#include <stdint.h>

typedef __attribute__((ext_vector_type(4))) float f32x4;
typedef __attribute__((ext_vector_type(8))) short bf16x8;
typedef __attribute__((ext_vector_type(4))) short bf16x4;
typedef __attribute__((ext_vector_type(4))) unsigned int u32x4;

__device__ __forceinline__ unsigned short f2bf_rne(float f) {
  union { float f; unsigned int u; } v; v.f = f;
  unsigned int r = v.u + 0x7FFFu + ((v.u >> 16) & 1u);
  return (unsigned short)(r >> 16);
}
__device__ __forceinline__ float bf2f(unsigned short s) {
  union { float f; unsigned int u; } v; v.u = ((unsigned int)s) << 16;
  return v.f;
}

// ---------------------------------------------------------------------------
// K1: per-batch Gram partials via split bf16 (H H^T + H L^T + L H^T).
// 8 n-chunks of 512, grid (8, 16 b, 2 halves) x 512 thr, dbuf LDS (1 barrier
// per sub). Upper-triangle tiles stored only (21 MB); k_reduce mirrors.
// ---------------------------------------------------------------------------
__global__ __launch_bounds__(512, 4) void k_gram(const float* __restrict__ x,
                                                 float* __restrict__ Gpart) {
  __shared__ __align__(16) unsigned char lds[2][32768];
  const int b = blockIdx.y;
  const int n0 = blockIdx.x << 9;
  const int half = blockIdx.z;
  const int t = threadIdx.x;
  const int lane = t & 63;
  const int w = t >> 6;                    // 0..7
  const int ti = (half << 1) + (w >> 2);   // output tile row 0..3
  const int tj = w & 3;                    // output tile col 0..3
  const int wm = ti << 6;
  const int wn = tj << 6;
  const int row_ld = t >> 1;               // c row this thread stages
  const int nh = t & 1;                    // 16-float half of the 32-n sub
  const int lrow = lane & 15;
  const int lkg = lane >> 4;

  f32x4 acc[4][4];
#pragma unroll
  for (int i = 0; i < 4; i++)
#pragma unroll
    for (int j = 0; j < 4; j++) acc[i][j] = (f32x4){0.f, 0.f, 0.f, 0.f};

  const float* gx = x + (((size_t)(b * 256 + row_ld)) << 12) + n0 + (nh << 4);

  for (int sub = 0; sub < 16; sub++) {
    unsigned char* buf = lds[sub & 1];
    f32x4 v0 = *(const f32x4*)(gx + (sub << 5));
    f32x4 v1 = *(const f32x4*)(gx + (sub << 5) + 4);
    f32x4 v2 = *(const f32x4*)(gx + (sub << 5) + 8);
    f32x4 v3 = *(const f32x4*)(gx + (sub << 5) + 12);
    float vv[16] = {v0[0], v0[1], v0[2], v0[3], v1[0], v1[1], v1[2], v1[3],
                    v2[0], v2[1], v2[2], v2[3], v3[0], v3[1], v3[2], v3[3]};
    unsigned short hi[16], lo[16];
#pragma unroll
    for (int j = 0; j < 16; j++) {
      hi[j] = f2bf_rne(vv[j]);
      lo[j] = f2bf_rne(vv[j] - bf2f(hi[j]));
    }
    u32x4 hw0 = {(unsigned)hi[0] | ((unsigned)hi[1] << 16),
                 (unsigned)hi[2] | ((unsigned)hi[3] << 16),
                 (unsigned)hi[4] | ((unsigned)hi[5] << 16),
                 (unsigned)hi[6] | ((unsigned)hi[7] << 16)};
    u32x4 hw1 = {(unsigned)hi[8] | ((unsigned)hi[9] << 16),
                 (unsigned)hi[10] | ((unsigned)hi[11] << 16),
                 (unsigned)hi[12] | ((unsigned)hi[13] << 16),
                 (unsigned)hi[14] | ((unsigned)hi[15] << 16)};
    u32x4 lw0 = {(unsigned)lo[0] | ((unsigned)lo[1] << 16),
                 (unsigned)lo[2] | ((unsigned)lo[3] << 16),
                 (unsigned)lo[4] | ((unsigned)lo[5] << 16),
                 (unsigned)lo[6] | ((unsigned)lo[7] << 16)};
    u32x4 lw1 = {(unsigned)lo[8] | ((unsigned)lo[9] << 16),
                 (unsigned)lo[10] | ((unsigned)lo[11] << 16),
                 (unsigned)lo[12] | ((unsigned)lo[13] << 16),
                 (unsigned)lo[14] | ((unsigned)lo[15] << 16)};
    const int swz = (row_ld & 7) << 4;
    unsigned char* rbase = buf + row_ld * 128;
    *(u32x4*)(rbase + (((nh << 5)) ^ swz)) = hw0;            // H region
    *(u32x4*)(rbase + (((nh << 5) + 16) ^ swz)) = hw1;
    *(u32x4*)(rbase + ((64 + (nh << 5)) ^ swz)) = lw0;       // L region
    *(u32x4*)(rbase + ((64 + (nh << 5) + 16) ^ swz)) = lw1;
    __syncthreads();  // dbuf: one barrier/sub

    bf16x8 bh[4], bl[4];
#pragma unroll
    for (int nf = 0; nf < 4; nf++) {
      int col = wn + (nf << 4) + lrow;
      int cs = (col & 7) << 4;
      bh[nf] = *(const bf16x8*)(buf + col * 128 + (((lkg << 4)) ^ cs));
      bl[nf] = *(const bf16x8*)(buf + col * 128 + ((64 + (lkg << 4)) ^ cs));
    }
#pragma unroll
    for (int mf = 0; mf < 4; mf++) {
      int row = wm + (mf << 4) + lrow;
      int rs = (row & 7) << 4;
      bf16x8 ah = *(const bf16x8*)(buf + row * 128 + (((lkg << 4)) ^ rs));
      bf16x8 al = *(const bf16x8*)(buf + row * 128 + ((64 + (lkg << 4)) ^ rs));
#pragma unroll
      for (int nf = 0; nf < 4; nf++) {
        acc[mf][nf] = __builtin_amdgcn_mfma_f32_16x16x32_bf16(ah, bh[nf], acc[mf][nf], 0, 0, 0);
        acc[mf][nf] = __builtin_amdgcn_mfma_f32_16x16x32_bf16(ah, bl[nf], acc[mf][nf], 0, 0, 0);
        acc[mf][nf] = __builtin_amdgcn_mfma_f32_16x16x32_bf16(al, bh[nf], acc[mf][nf], 0, 0, 0);
      }
    }
  }

  if (tj >= ti) {  // upper-triangle tiles only (G symmetric)
    float* Gp = Gpart + (((size_t)(blockIdx.x * 16 + b)) << 16);
#pragma unroll
    for (int mf = 0; mf < 4; mf++)
#pragma unroll
      for (int nf = 0; nf < 4; nf++) {
        int col = wn + (nf << 4) + lrow;
#pragma unroll
        for (int r = 0; r < 4; r++) {
          int row = wm + (mf << 4) + (lkg << 2) + r;
          Gp[row * 256 + col] = acc[mf][nf][r];
        }
      }
  }
}

// ---------------------------------------------------------------------------
// K1b: 640 blocks x 256 thr: block = (b, upper tile i<=j, 16-row slab q).
// Sums the 8 chunk-partials of its slab, writes it + (i<j) the transposed
// mirror (proven round-6 code, ch<8).
// ---------------------------------------------------------------------------
__global__ __launch_bounds__(256) void k_reduce(const float* __restrict__ Gpart,
                                                float* __restrict__ G) {
  __shared__ float tl[16][68];
  const int bx = blockIdx.x;        // 16 b x 10 tile-pairs x 4 slabs
  const int b = bx / 40;
  const int rem = bx % 40;
  const int tp = rem >> 2, q = rem & 3;
  const int TI[10] = {0, 0, 0, 0, 1, 1, 1, 2, 2, 3};
  const int TJ[10] = {0, 1, 2, 3, 1, 2, 3, 2, 3, 3};
  const int i = TI[tp], j = TJ[tp];
  const int t = threadIdx.x;
  const int r = t >> 4, cq = t & 15;
  const int row = i * 64 + (q << 4) + r;

  const float* src = Gpart + ((size_t)b << 16) + (size_t)row * 256 + j * 64 + (cq << 2);
  f32x4 s = *(const f32x4*)(src);
#pragma unroll
  for (int ch = 1; ch < 8; ch++)
    s += *(const f32x4*)(src + (((size_t)ch) << 20));
  *(f32x4*)(G + ((size_t)b << 16) + (size_t)row * 256 + j * 64 + (cq << 2)) = s;

  if (i != j) {
    *(f32x4*)&tl[r][cq << 2] = s;
    __syncthreads();
    const int c = t >> 2, g = t & 3;  // mirror row c (0..63), 4-float group g
    f32x4 m;
#pragma unroll
    for (int k = 0; k < 4; k++) m[k] = tl[(g << 2) + k][c];
    *(f32x4*)(G + ((size_t)b << 16) + (size_t)(j * 64 + c) * 256 + i * 64 + (q << 4) + (g << 2)) = m;
  }
}

// ---------------------------------------------------------------------------
// K2: T = Wq_rows·G (c-split over 8 waves; Wq via wave-uniform scalar loads),
// LDS partial-reduce; scores + softmax -> attn; Wout rows via shfl(A) +
// coalesced Wv rows. grid (8 h, 16 b, 2 dg) x 512. Reads the 4 MB G (hot).
// ---------------------------------------------------------------------------
__global__ __launch_bounds__(512) void k_scores(const float* __restrict__ wq,
                                                const float* __restrict__ wk,
                                                const float* __restrict__ wv,
                                                const float* __restrict__ G,
                                                float* __restrict__ attn,
                                                unsigned short* __restrict__ Wout) {
  __shared__ float part[8][16][256];  // 128 KB; part[0] becomes T after reduce
  const int h = blockIdx.x, b = blockIdx.y, dg = blockIdx.z;
  const int t = threadIdx.x, lane = t & 63;
  const int wu = __builtin_amdgcn_readfirstlane(t >> 6);  // wave id, uniform

  // ---- Phase 1: T[d][cp] = sum_c Wq[h*32+dg*16+d][c] * G[b][c][cp] ----
  const float* wqrow = wq + (size_t)(h * 32 + dg * 16) * 256 + wu * 32;  // uniform
  f32x4 tp[16];
#pragma unroll
  for (int d = 0; d < 16; d++) tp[d] = (f32x4){0.f, 0.f, 0.f, 0.f};

  const float* Gb = G + ((size_t)b << 16) + (size_t)(wu * 32) * 256 + (lane << 2);
  for (int s = 0; s < 32; s++) {
    f32x4 g = *(const f32x4*)(Gb + s * 256);
#pragma unroll
    for (int d = 0; d < 16; d++)
      tp[d] += g * wqrow[d * 256 + s];  // uniform index -> s_load (SMEM pipe)
  }
#pragma unroll
  for (int d = 0; d < 16; d++)
    *(f32x4*)&part[wu][d][lane << 2] = tp[d];
  __syncthreads();

  // in-place reduce into part[0]: each thread owns 2 f32x4 output slots
#pragma unroll
  for (int u = 0; u < 2; u++) {
    int o = t * 2 + u;  // [0,1024) = 16 d x 64 quads
    int d = o >> 6, q = (o & 63) << 2;
    f32x4 s = *(f32x4*)&part[0][d][q];
#pragma unroll
    for (int w2 = 1; w2 < 8; w2++) s += *(f32x4*)&part[w2][d][q];
    *(f32x4*)&part[0][d][q] = s;
  }
  __syncthreads();
  const float* Tb = &part[0][0][0];

  // ---- Phase 2: scores + softmax (thread = (dls = t>>5, es = t&31)) ----
  const int dls = t >> 5, es = t & 31;
  f32x4 sa = {0.f, 0.f, 0.f, 0.f};
  const float* Tr = Tb + dls * 256;
  const float* wkr = wk + (size_t)(h * 32 + es) * 256;
  for (int c4 = 0; c4 < 64; c4++)
    sa += *(const f32x4*)(Tr + (c4 << 2)) * *(const f32x4*)(wkr + (c4 << 2));
  float s = (sa[0] + sa[1] + sa[2] + sa[3]) * 0.35355339059327379f;

  float m = s;
#pragma unroll
  for (int off = 1; off < 32; off <<= 1) m = fmaxf(m, __shfl_xor(m, off));
  float p = expf(s - m);
  float su = p;
#pragma unroll
  for (int off = 1; off < 32; off <<= 1) su += __shfl_xor(su, off);
  float a = p / su;
  attn[(((b * 8 + h) * 32) + dg * 16 + dls) * 32 + es] = a;

  // ---- Phase 3: wave wu owns rows {2wu, 2wu+1}; A broadcast via shfl ----
  f32x4 o0 = {0.f, 0.f, 0.f, 0.f}, o1 = {0.f, 0.f, 0.f, 0.f};
  const float* wvh = wv + (size_t)(h * 32) * 256 + (lane << 2);
#pragma unroll
  for (int e = 0; e < 32; e++) {
    float a0 = __shfl(a, e);
    float a1 = __shfl(a, 32 + e);
    f32x4 vv = *(const f32x4*)(wvh + e * 256);
    o0 += vv * a0;
    o1 += vv * a1;
  }
  const int d0 = dg * 16 + 2 * wu;
  const int co0 = d0 * 8 + h, co1 = (d0 + 1) * 8 + h;
  o0 += *(const f32x4*)(wv + (size_t)co0 * 256 + (lane << 2));
  o1 += *(const f32x4*)(wv + (size_t)co1 * 256 + (lane << 2));
  bf16x4 p0, p1;
#pragma unroll
  for (int j = 0; j < 4; j++) {
    p0[j] = (short)f2bf_rne(o0[j]);
    p1[j] = (short)f2bf_rne(o1[j]);
  }
  *(bf16x4*)(Wout + ((size_t)(b * 256 + co0) << 8) + (lane << 2)) = p0;
  *(bf16x4*)(Wout + ((size_t)(b * 256 + co1) << 8) + (lane << 2)) = p1;
}

// ---------------------------------------------------------------------------
// K3: out[b] = W_out_b (bf16) x bf16(x[b]), fp32 out. x read fp32 (L3-hot),
// converted in-kernel; double-buffered Bt (1 barrier/kt); tr_b16 B-frag path.
// grid (32 n-chunks, 16 b) x 512 thr.
// ---------------------------------------------------------------------------
__global__ __launch_bounds__(512) void k_out(const float* __restrict__ x,
                                             const unsigned short* __restrict__ Wout,
                                             float* __restrict__ out) {
  __shared__ __align__(16) unsigned short Bt[2][4096];  // 2 x (32c x 128n)
  const int b = blockIdx.y;
  const int nb = blockIdx.x << 7;
  const int t = threadIdx.x;
  const int lane = t & 63;
  const int w = t >> 6;
  const int wm = (w >> 1) << 6;
  const int wn = (w & 1) << 6;
  const int lrow = lane & 15;
  const int lkg = lane >> 4;

  f32x4 acc[4][4];
#pragma unroll
  for (int i = 0; i < 4; i++)
#pragma unroll
    for (int j = 0; j < 4; j++) acc[i][j] = (f32x4){0.f, 0.f, 0.f, 0.f};

  // staging lane map (m173 pattern): linear LDS dest <- permuted global src
  const int pos = lane >> 3;
  const int cblk = 2 * (pos & 3) + (pos >> 2);  // even cblks first, then odd
  const int ctil = cblk * 4 + ((lane & 7) >> 1);
  const int noff = (lane & 1) << 3;
  const float* gxb = x + (((size_t)b) << 20) + (size_t)ctil * 4096 + nb + (w << 4) + noff;
  const unsigned int bt0 = (unsigned int)(uintptr_t)(&Bt[0][0]);

  f32x4 xa = *(const f32x4*)(gxb);
  f32x4 xb = *(const f32x4*)(gxb + 4);

  for (int kt = 0; kt < 8; kt++) {
    const int p = kt & 1;
    bf16x8 pk;
#pragma unroll
    for (int j = 0; j < 4; j++) {
      pk[j] = (short)f2bf_rne(xa[j]);
      pk[4 + j] = (short)f2bf_rne(xb[j]);
    }
    *(bf16x8*)(&Bt[p][(w << 9) + (lane << 3)]) = pk;
    __syncthreads();  // single barrier/kt

    if (kt < 7) {  // prefetch next k-tile under MFMA
      const float* nx = gxb + (((size_t)(kt + 1)) << 17);
      xa = *(const f32x4*)(nx);
      xb = *(const f32x4*)(nx + 4);
    }

    bf16x8 afr[4];
    const unsigned short* wrow = Wout + (((size_t)(b * 256)) << 8) + kt * 32 + (lkg << 3);
#pragma unroll
    for (int mf = 0; mf < 4; mf++) {
      int co = wm + (mf << 4) + lrow;
      afr[mf] = *(const bf16x8*)(wrow + ((size_t)co << 8));
    }

    bf16x4 t0[4], t1[4];
#pragma unroll
    for (int nf = 0; nf < 4; nf++) {
      unsigned int base = bt0 + (unsigned int)(p << 13) +
                          (unsigned int)((((wn >> 4) + nf)) << 10) + (lane << 3);
      asm volatile("ds_read_b64_tr_b16 %0, %1" : "=v"(t0[nf]) : "v"(base) : "memory");
      asm volatile("ds_read_b64_tr_b16 %0, %1 offset:512" : "=v"(t1[nf]) : "v"(base) : "memory");
    }
    asm volatile("s_waitcnt lgkmcnt(0)" ::: "memory");
    __builtin_amdgcn_sched_barrier(0);

    bf16x8 bfr[4];
#pragma unroll
    for (int nf = 0; nf < 4; nf++) {
      bfr[nf][0] = t0[nf][0]; bfr[nf][1] = t0[nf][1];
      bfr[nf][2] = t0[nf][2]; bfr[nf][3] = t0[nf][3];
      bfr[nf][4] = t1[nf][0]; bfr[nf][5] = t1[nf][1];
      bfr[nf][6] = t1[nf][2]; bfr[nf][7] = t1[nf][3];
    }
#pragma unroll
    for (int mf = 0; mf < 4; mf++)
#pragma unroll
      for (int nf = 0; nf < 4; nf++)
        acc[mf][nf] = __builtin_amdgcn_mfma_f32_16x16x32_bf16(afr[mf], bfr[nf], acc[mf][nf], 0, 0, 0);
  }

  float* ob = out + (((size_t)b) << 20) + nb;
#pragma unroll
  for (int mf = 0; mf < 4; mf++)
#pragma unroll
    for (int nf = 0; nf < 4; nf++) {
      int col = wn + (nf << 4) + lrow;
#pragma unroll
      for (int r = 0; r < 4; r++) {
        int row = wm + (mf << 4) + (lkg << 2) + r;
        ob[((size_t)row << 12) + col] = acc[mf][nf][r];
      }
    }
}

// ---------------------------------------------------------------------------
extern "C" void kernel_launch(void* const* d_in, const int* in_sizes, int n_in,
                              void* d_out, int out_size, void* d_ws, size_t ws_size,
                              hipStream_t stream) {
  const float* x = (const float*)d_in[0];
  const float* wq = (const float*)d_in[1];
  const float* wk = (const float*)d_in[2];
  const float* wv = (const float*)d_in[3];
  float* out = (float*)d_out;
  float* attn = out + (size_t)16 * 256 * 4096;

  // Gpart: 8 chunks x 16 b x 256 KB = 33.5 MB (upper-tri tiles written),
  // lives in the dead-until-K3 out region; attn tail is disjoint.
  float* Gpart = out;

  char* ws = (char*)d_ws;
  float* G = (float*)ws;                                     // 4 MB
  unsigned short* Wout = (unsigned short*)(ws + (4 << 20));  // 2 MB

  k_gram<<<dim3(8, 16, 2), dim3(512), 0, stream>>>(x, Gpart);
  k_reduce<<<dim3(640), dim3(256), 0, stream>>>(Gpart, G);
  k_scores<<<dim3(8, 16, 2), dim3(512), 0, stream>>>(wq, wk, wv, G, attn, Wout);
  k_out<<<dim3(32, 16), dim3(512), 0, stream>>>(x, Wout, out);
}